// Round 4
// baseline (224.003 us; speedup 1.0000x reference)
//
#include <hip/hip_runtime.h>
#include <math.h>

// Problem constants: B=128, C=48, H=W=64, p=32, N=4, D=49152
#define PLANE 4096            // 64*64
#define OUT0 25165824         // 128*48*64*64 (flat offset of logdet output)

typedef float fx4 __attribute__((ext_vector_type(4)));

// ws layout (floats):
#define WS_GT   0             // [2304]  GT[k*48+r] = G[r][k]
#define WS_PART 4096          // [128*2*4] score sums per (b, s): {s11,s12,s21,s22}

// ---------------- k0: GT[k*48+r] = sum_o Wq[o,r]*Wk[o,k] (3 pairs), LDS-staged W;
//                  also zeroes part[] (replaces the hipMemsetAsync dispatch) ----
__global__ __launch_bounds__(256) void g_kernel(const float* __restrict__ Wq1,
                                                const float* __restrict__ Wq2,
                                                const float* __restrict__ Wq3,
                                                const float* __restrict__ Wk1,
                                                const float* __restrict__ Wk2,
                                                const float* __restrict__ Wk3,
                                                float* __restrict__ GT,
                                                float* __restrict__ part) {
    __shared__ float Ws[6][2304];
    int tid = threadIdx.x;
    int idx = blockIdx.x * 256 + tid;     // grid 9*256 = 2304 exactly
    if (idx < 1024) part[idx] = 0.f;

    for (int i = tid; i < 2304; i += 256) {
        Ws[0][i] = Wq1[i];
        Ws[1][i] = Wk1[i];
        Ws[2][i] = Wq2[i];
        Ws[3][i] = Wk2[i];
        Ws[4][i] = Wq3[i];
        Ws[5][i] = Wk3[i];
    }
    __syncthreads();

    int k = idx / 48, r = idx % 48;       // GT[k*48+r] = G[r][k]
    float acc = 0.f;
#pragma unroll 8
    for (int o = 0; o < 48; ++o) {
        acc = fmaf(Ws[0][o * 48 + r], Ws[1][o * 48 + k], acc);
        acc = fmaf(Ws[2][o * 48 + r], Ws[3][o * 48 + k], acc);
        acc = fmaf(Ws[4][o * 48 + r], Ws[5][o * 48 + k], acc);
    }
    GT[idx] = acc;
}

// ---------------- k1: scores via r-split quadratic forms ----------
// grid 2048 = b(128) x g(16 groups of 2 i-rows); block 256 = 4 waves.
// Full-tile LINEAR staging (48 KB, no compaction): Xf[c][row:4][w:64].
// Parity selection moves into the READ address: w = 33*s + 2*jj
//   -> s=0 lanes hit even banks, s=1 lanes odd banks: 2 lanes/bank = free.
// Wave = r-chunk (wave-uniform -> G via scalar loads, zero LDS cost).
// No in-loop capture: the 12 (t,v) pairs needed for the final dot are
// re-read from LDS post-loop (24 ds_read_b32, immediate offsets).
__global__ __launch_bounds__(256, 3) void score_kernel(const float* __restrict__ x,
                                                       const float* __restrict__ GT,
                                                       float* __restrict__ part) {
    __shared__ float Xf[48 * 4 * 64];     // [c][row][w] = 48 KB
    __shared__ float red[4][2][4];
    int tid = threadIdx.x;
    int bid = blockIdx.x;
    int g = bid & 15;                     // 16 groups of 2 i-rows
    int b = bid >> 4;

    // ---- stage: 3072 fx4, fully linear LDS dest, coalesced global src.
    const float* xb = x + (size_t)b * (48 * PLANE);
#pragma unroll
    for (int t = 0; t < 12; ++t) {
        int l = t * 256 + tid;            // linear fx4 index 0..3071
        int c = l >> 6;                   // 0..47
        int row = (l >> 4) & 3;           // 0,1 top; 2,3 bottom
        int w4 = l & 15;
        int h = 2 * g + (row & 1) + ((row >> 1) << 5);
        fx4 d = *(const fx4*)(xb + c * PLANE + h * 64 + w4 * 4);
        *(fx4*)(Xf + l * 4) = d;          // Xf[(c*4+row)*64 + w4*4]
    }
    __syncthreads();

    // ---- compute: wave = r-chunk, lane = (s, il, jj)
    int rc = __builtin_amdgcn_readfirstlane(tid >> 6);   // wave-uniform r-chunk
    int lane = tid & 63;
    int s = lane >> 5;
    int il = (lane >> 4) & 1;
    int jj = lane & 15;
    int w = 33 * s + 2 * jj;              // masked-parity column for this s

    const float* X0 = &Xf[il * 64 + w];
    // t = X0[k*256] (row il), v = X0[k*256 + 128] (row il+2); both 2-way bank = free.

    const float* __restrict__ gbase = GT + rc * 12;      // uniform -> s_load path

    float u1[12], u2[12];
#pragma unroll
    for (int j = 0; j < 12; ++j) { u1[j] = 0.f; u2[j] = 0.f; }

#pragma unroll
    for (int k = 0; k < 48; ++k) {
        float t = X0[k * 256];
        float v = X0[k * 256 + 128];
        fx4 gA = *(const fx4*)(gbase + k * 48);       // G[rc*12+0..3][k]
        fx4 gB = *(const fx4*)(gbase + k * 48 + 4);
        fx4 gC = *(const fx4*)(gbase + k * 48 + 8);
#pragma unroll
        for (int j = 0; j < 4; ++j) {
            u1[j]     = fmaf(gA[j], t, u1[j]);
            u2[j]     = fmaf(gA[j], v, u2[j]);
            u1[j + 4] = fmaf(gB[j], t, u1[j + 4]);
            u2[j + 4] = fmaf(gB[j], v, u2[j + 4]);
            u1[j + 8] = fmaf(gC[j], t, u1[j + 8]);
            u2[j + 8] = fmaf(gC[j], v, u2[j + 8]);
        }
    }

    // ---- final dots: re-read this r-chunk's 12 (t,v) pairs from LDS
    const float* X2 = X0 + rc * 12 * 256;
    float s11 = 0.f, s12 = 0.f, s21 = 0.f, s22 = 0.f;
#pragma unroll
    for (int j = 0; j < 12; ++j) {
        float tj = X2[j * 256];
        float vj = X2[j * 256 + 128];
        s11 = fmaf(tj, u1[j], s11);       // (top,top)
        s12 = fmaf(tj, u2[j], s12);       // (top,bot)
        s21 = fmaf(vj, u1[j], s21);       // (bot,top)
        s22 = fmaf(vj, u2[j], s22);       // (bot,bot)
    }

    // butterfly over lane bits 0..4 (jj, il) — keeps the two s-halves separate
#pragma unroll
    for (int off = 1; off < 32; off <<= 1) {
        s11 += __shfl_xor(s11, off, 64);
        s12 += __shfl_xor(s12, off, 64);
        s21 += __shfl_xor(s21, off, 64);
        s22 += __shfl_xor(s22, off, 64);
    }
    if ((lane & 31) == 0) {               // lane 0 -> s=0 sums, lane 32 -> s=1 sums
        red[rc][s][0] = s11; red[rc][s][1] = s12; red[rc][s][2] = s21; red[rc][s][3] = s22;
    }
    __syncthreads();
    if (tid < 8) {
        int so = tid >> 2, q = tid & 3;
        float tot = red[0][so][q] + red[1][so][q] + red[2][so][q] + red[3][so][q];
        atomicAdd(&part[(b * 2 + so) * 4 + q], tot);
    }
}

// ---------------- k2: streaming output + fused attn/softmax/logdet ----------------
__global__ __launch_bounds__(256) void out_kernel(const float* __restrict__ x,
                                                  const float* __restrict__ part,
                                                  const float* __restrict__ logdet_in,
                                                  const float* __restrict__ off_p,
                                                  const float* __restrict__ off2_p,
                                                  float* __restrict__ out,
                                                  float* __restrict__ out_logdet) {
    int bc = blockIdx.x;            // 128*48
    int b = bc / 48;

    const float inv_scale = 4.5105361e-3f;   // 1/sqrt(49152)
    float off = off_p[0];
    float c2o = off2_p[0];
    float ld = 0.f;
    float Ad[4], Ao[4];
#pragma unroll
    for (int s = 0; s < 2; ++s) {
        int base = (b * 2 + s) * 4;
        float stt = part[base + 0] * inv_scale;
        float stb = part[base + 1] * inv_scale;
        float sbt = part[base + 2] * inv_scale;
        float sbb = part[base + 3] * inv_scale;

        float m0 = fmaxf(fmaxf(stt, stb), 0.f);
        float e00 = expf(stt - m0), e01 = expf(stb - m0), ez0 = expf(-m0);
        float d0 = e00 + e01 + 2.f * ez0;
        float ptt = e00 / d0, ptb = e01 / d0;
        float m1 = fmaxf(fmaxf(sbt, sbb), 0.f);
        float e10 = expf(sbt - m1), e11 = expf(sbb - m1), ez1 = expf(-m1);
        float d1 = e10 + e11 + 2.f * ez1;
        float pbt = e10 / d1, pbb = e11 / d1;

        float adt = ptt + c2o + off;
        float aot = ptb + c2o;
        float adb = pbb + c2o + off;
        float aob = pbt + c2o;
        Ad[s] = adt; Ao[s] = aot; Ad[s + 2] = adb; Ao[s + 2] = aob;
        float det = adt * adb - aot * aob;
        ld += logf(fabsf(det));
    }
    if ((bc - b * 48) == 0 && threadIdx.x == 0) {
        out_logdet[b] = logdet_in[b] + ld * 24576.0f;
    }

    const fx4* xb4 = (const fx4*)(x + (size_t)bc * PLANE);
    fx4* ob4 = (fx4*)(out + (size_t)bc * PLANE);
    int tid = threadIdx.x;
#pragma unroll
    for (int it = 0; it < 2; ++it) {
        int f = it * 256 + tid;       // 0..511
        int h = f >> 4;               // 0..31
        int w4 = f & 15;
        fx4 xt = __builtin_nontemporal_load(&xb4[h * 16 + w4]);
        fx4 xv = __builtin_nontemporal_load(&xb4[(h + 32) * 16 + w4]);
        int wb = w4 >> 3;
        float Adt = wb ? Ad[1] : Ad[0];
        float Aot = wb ? Ao[1] : Ao[0];
        float Adb = wb ? Ad[3] : Ad[2];
        float Aob = wb ? Ao[3] : Ao[2];

        fx4 rt, rv;
#pragma unroll
        for (int q = 0; q < 4; ++q) {
            int e = (wb + q) & 1;
            float t = xt[q], v = xv[q];
            float mt = fmaf(Adt, t, Aot * v);
            float mv = fmaf(Adb, v, Aob * t);
            rt[q] = e ? mt : t;
            rv[q] = e ? mv : v;
        }
        __builtin_nontemporal_store(rt, &ob4[h * 16 + w4]);
        __builtin_nontemporal_store(rv, &ob4[(h + 32) * 16 + w4]);
    }
}

extern "C" void kernel_launch(void* const* d_in, const int* in_sizes, int n_in,
                              void* d_out, int out_size, void* d_ws, size_t ws_size,
                              hipStream_t stream) {
    const float* x      = (const float*)d_in[0];
    const float* logdet = (const float*)d_in[1];
    const float* Wq1    = (const float*)d_in[2];
    const float* Wq2    = (const float*)d_in[3];
    const float* Wq3    = (const float*)d_in[4];
    const float* Wk1    = (const float*)d_in[5];
    const float* Wk2    = (const float*)d_in[6];
    const float* Wk3    = (const float*)d_in[7];
    const float* off    = (const float*)d_in[8];
    const float* off2   = (const float*)d_in[9];
    // d_in[10] (offset3) is a uniform pre-softmax shift -> cancels; unused.

    float* out = (float*)d_out;
    float* ws  = (float*)d_ws;
    float* GT   = ws + WS_GT;
    float* part = ws + WS_PART;

    g_kernel<<<9, 256, 0, stream>>>(Wq1, Wq2, Wq3, Wk1, Wk2, Wk3, GT, part);
    score_kernel<<<2048, 256, 0, stream>>>(x, GT, part);
    out_kernel<<<6144, 256, 0, stream>>>(x, part, logdet, off, off2, out, out + OUT0);
}

// Round 5
// 218.899 us; speedup vs baseline: 1.0233x; 1.0233x over previous
//
#include <hip/hip_runtime.h>
#include <math.h>

// Problem constants: B=128, C=48, H=W=64, p=32, N=4, D=49152
#define PLANE 4096            // 64*64
#define OUT0 25165824         // 128*48*64*64 (flat offset of logdet output)

typedef float fx4 __attribute__((ext_vector_type(4)));

// ws layout (floats):
#define WS_GT   0             // [2304]  GT[k*48+r] = G[r][k]
#define WS_PART 4096          // [128*2*4] score sums per (b, s): {s11,s12,s21,s22}

// ---------------- k0: GT[k*48+r] = sum_o Wq[o,r]*Wk[o,k] (3 pairs), LDS-staged W;
//                  also zeroes part[] (replaces the hipMemsetAsync dispatch) ----
__global__ __launch_bounds__(256) void g_kernel(const float* __restrict__ Wq1,
                                                const float* __restrict__ Wq2,
                                                const float* __restrict__ Wq3,
                                                const float* __restrict__ Wk1,
                                                const float* __restrict__ Wk2,
                                                const float* __restrict__ Wk3,
                                                float* __restrict__ GT,
                                                float* __restrict__ part) {
    __shared__ float Ws[6][2304];
    int tid = threadIdx.x;
    int idx = blockIdx.x * 256 + tid;     // grid 9*256 = 2304 exactly
    if (idx < 1024) part[idx] = 0.f;

    for (int i = tid; i < 2304; i += 256) {
        Ws[0][i] = Wq1[i];
        Ws[1][i] = Wk1[i];
        Ws[2][i] = Wq2[i];
        Ws[3][i] = Wk2[i];
        Ws[4][i] = Wq3[i];
        Ws[5][i] = Wk3[i];
    }
    __syncthreads();

    int k = idx / 48, r = idx % 48;       // GT[k*48+r] = G[r][k]
    float acc = 0.f;
#pragma unroll 8
    for (int o = 0; o < 48; ++o) {
        acc = fmaf(Ws[0][o * 48 + r], Ws[1][o * 48 + k], acc);
        acc = fmaf(Ws[2][o * 48 + r], Ws[3][o * 48 + k], acc);
        acc = fmaf(Ws[4][o * 48 + r], Ws[5][o * 48 + k], acc);
    }
    GT[idx] = acc;
}

// ---------------- k1: scores via r-split quadratic forms ----------
// grid 2048 = b(128) x g(16 groups of 2 i-rows); block 256 = 4 waves.
// Parity-COMPACTED staging: Xc[s:2][c:48][row:4][jj:16] = 24 KB -> 6 blocks/CU
// (vs 48 KB full-tile = 3 blocks/CU in the previous round). Doubled residency
// is the lever: stage (HBM) of some blocks overlaps compute (VALU/LDS) of others.
// Read banks: t at il*16+jj, v at same set; s-halves alias 2-way = free.
// Write: float2, 4-way on 12 instrs/thread -- negligible.
// Wave = r-chunk (wave-uniform -> G via scalar loads, zero LDS-pipe cost).
__global__ __launch_bounds__(256, 6) void score_kernel(const float* __restrict__ x,
                                                       const float* __restrict__ GT,
                                                       float* __restrict__ part) {
    __shared__ float Xc[2 * 48 * 4 * 16];  // [s][c][row][jj] = 24 KB
    __shared__ float red[4][2][4];
    int tid = threadIdx.x;
    int bid = blockIdx.x;
    int g = bid & 15;                     // 16 groups of 2 i-rows
    int b = bid >> 4;

    // ---- stage: fx4-coalesced global loads, parity-compacted LDS writes.
    const float* xb = x + (size_t)b * (48 * PLANE);
#pragma unroll
    for (int t = 0; t < 12; ++t) {
        int l = t * 256 + tid;            // linear fx4 index 0..3071
        int c = l >> 6;                   // 0..47
        int row = (l >> 4) & 3;           // 0,1 top; 2,3 bottom
        int w4 = l & 15;                  // fx4 index within the 64-col row
        int h = 2 * g + (row & 1) + ((row >> 1) << 5);
        fx4 d = *(const fx4*)(xb + c * PLANE + h * 64 + w4 * 4);
        int s = w4 >> 3;                  // left half -> s=0 (even cols), right -> s=1 (odd)
        int w4p = w4 & 7;
        float2 pr;                        // the two parity-s elements of this fx4
        pr.x = s ? d[1] : d[0];           // col 33*s + 2*(2*w4p)
        pr.y = s ? d[3] : d[2];           // col 33*s + 2*(2*w4p+1)
        *(float2*)(&Xc[((s * 48 + c) * 4 + row) * 16 + 2 * w4p]) = pr;
    }
    __syncthreads();

    // ---- compute: wave = r-chunk, lane = (s, il, jj)
    int rc = __builtin_amdgcn_readfirstlane(tid >> 6);   // wave-uniform r-chunk
    int lane = tid & 63;
    int s = lane >> 5;
    int il = (lane >> 4) & 1;
    int jj = lane & 15;

    const float* X0 = &Xc[(s * 48 * 4 + il) * 16 + jj];
    // t = X0[k*64] (row il), v = X0[k*64 + 32] (row il+2); 2-way bank = free.

    const float* __restrict__ gbase = GT + rc * 12;      // uniform -> s_load path

    float u1[12], u2[12];
#pragma unroll
    for (int j = 0; j < 12; ++j) { u1[j] = 0.f; u2[j] = 0.f; }

#pragma unroll
    for (int k = 0; k < 48; ++k) {
        float t = X0[k * 64];
        float v = X0[k * 64 + 32];
        fx4 gA = *(const fx4*)(gbase + k * 48);       // G[rc*12+0..3][k]
        fx4 gB = *(const fx4*)(gbase + k * 48 + 4);
        fx4 gC = *(const fx4*)(gbase + k * 48 + 8);
#pragma unroll
        for (int j = 0; j < 4; ++j) {
            u1[j]     = fmaf(gA[j], t, u1[j]);
            u2[j]     = fmaf(gA[j], v, u2[j]);
            u1[j + 4] = fmaf(gB[j], t, u1[j + 4]);
            u2[j + 4] = fmaf(gB[j], v, u2[j + 4]);
            u1[j + 8] = fmaf(gC[j], t, u1[j + 8]);
            u2[j + 8] = fmaf(gC[j], v, u2[j + 8]);
        }
    }

    // ---- final dots: re-read this r-chunk's 12 (t,v) pairs from LDS
    const float* X2 = X0 + rc * 12 * 64;
    float s11 = 0.f, s12 = 0.f, s21 = 0.f, s22 = 0.f;
#pragma unroll
    for (int j = 0; j < 12; ++j) {
        float tj = X2[j * 64];
        float vj = X2[j * 64 + 32];
        s11 = fmaf(tj, u1[j], s11);       // (top,top)
        s12 = fmaf(tj, u2[j], s12);       // (top,bot)
        s21 = fmaf(vj, u1[j], s21);       // (bot,top)
        s22 = fmaf(vj, u2[j], s22);       // (bot,bot)
    }

    // butterfly over lane bits 0..4 (jj, il) — keeps the two s-halves separate
#pragma unroll
    for (int off = 1; off < 32; off <<= 1) {
        s11 += __shfl_xor(s11, off, 64);
        s12 += __shfl_xor(s12, off, 64);
        s21 += __shfl_xor(s21, off, 64);
        s22 += __shfl_xor(s22, off, 64);
    }
    if ((lane & 31) == 0) {               // lane 0 -> s=0 sums, lane 32 -> s=1 sums
        red[rc][s][0] = s11; red[rc][s][1] = s12; red[rc][s][2] = s21; red[rc][s][3] = s22;
    }
    __syncthreads();
    if (tid < 8) {
        int so = tid >> 2, q = tid & 3;
        float tot = red[0][so][q] + red[1][so][q] + red[2][so][q] + red[3][so][q];
        atomicAdd(&part[(b * 2 + so) * 4 + q], tot);
    }
}

// ---------------- k2: streaming output + fused attn/softmax/logdet ----------------
__global__ __launch_bounds__(256) void out_kernel(const float* __restrict__ x,
                                                  const float* __restrict__ part,
                                                  const float* __restrict__ logdet_in,
                                                  const float* __restrict__ off_p,
                                                  const float* __restrict__ off2_p,
                                                  float* __restrict__ out,
                                                  float* __restrict__ out_logdet) {
    int bc = blockIdx.x;            // 128*48
    int b = bc / 48;

    const float inv_scale = 4.5105361e-3f;   // 1/sqrt(49152)
    float off = off_p[0];
    float c2o = off2_p[0];
    float ld = 0.f;
    float Ad[4], Ao[4];
#pragma unroll
    for (int s = 0; s < 2; ++s) {
        int base = (b * 2 + s) * 4;
        float stt = part[base + 0] * inv_scale;
        float stb = part[base + 1] * inv_scale;
        float sbt = part[base + 2] * inv_scale;
        float sbb = part[base + 3] * inv_scale;

        float m0 = fmaxf(fmaxf(stt, stb), 0.f);
        float e00 = expf(stt - m0), e01 = expf(stb - m0), ez0 = expf(-m0);
        float d0 = e00 + e01 + 2.f * ez0;
        float ptt = e00 / d0, ptb = e01 / d0;
        float m1 = fmaxf(fmaxf(sbt, sbb), 0.f);
        float e10 = expf(sbt - m1), e11 = expf(sbb - m1), ez1 = expf(-m1);
        float d1 = e10 + e11 + 2.f * ez1;
        float pbt = e10 / d1, pbb = e11 / d1;

        float adt = ptt + c2o + off;
        float aot = ptb + c2o;
        float adb = pbb + c2o + off;
        float aob = pbt + c2o;
        Ad[s] = adt; Ao[s] = aot; Ad[s + 2] = adb; Ao[s + 2] = aob;
        float det = adt * adb - aot * aob;
        ld += logf(fabsf(det));
    }
    if ((bc - b * 48) == 0 && threadIdx.x == 0) {
        out_logdet[b] = logdet_in[b] + ld * 24576.0f;
    }

    const fx4* xb4 = (const fx4*)(x + (size_t)bc * PLANE);
    fx4* ob4 = (fx4*)(out + (size_t)bc * PLANE);
    int tid = threadIdx.x;
#pragma unroll
    for (int it = 0; it < 2; ++it) {
        int f = it * 256 + tid;       // 0..511
        int h = f >> 4;               // 0..31
        int w4 = f & 15;
        fx4 xt = __builtin_nontemporal_load(&xb4[h * 16 + w4]);
        fx4 xv = __builtin_nontemporal_load(&xb4[(h + 32) * 16 + w4]);
        int wb = w4 >> 3;
        float Adt = wb ? Ad[1] : Ad[0];
        float Aot = wb ? Ao[1] : Ao[0];
        float Adb = wb ? Ad[3] : Ad[2];
        float Aob = wb ? Ao[3] : Ao[2];

        fx4 rt, rv;
#pragma unroll
        for (int q = 0; q < 4; ++q) {
            int e = (wb + q) & 1;
            float t = xt[q], v = xv[q];
            float mt = fmaf(Adt, t, Aot * v);
            float mv = fmaf(Adb, v, Aob * t);
            rt[q] = e ? mt : t;
            rv[q] = e ? mv : v;
        }
        __builtin_nontemporal_store(rt, &ob4[h * 16 + w4]);
        __builtin_nontemporal_store(rv, &ob4[(h + 32) * 16 + w4]);
    }
}

extern "C" void kernel_launch(void* const* d_in, const int* in_sizes, int n_in,
                              void* d_out, int out_size, void* d_ws, size_t ws_size,
                              hipStream_t stream) {
    const float* x      = (const float*)d_in[0];
    const float* logdet = (const float*)d_in[1];
    const float* Wq1    = (const float*)d_in[2];
    const float* Wq2    = (const float*)d_in[3];
    const float* Wq3    = (const float*)d_in[4];
    const float* Wk1    = (const float*)d_in[5];
    const float* Wk2    = (const float*)d_in[6];
    const float* Wk3    = (const float*)d_in[7];
    const float* off    = (const float*)d_in[8];
    const float* off2   = (const float*)d_in[9];
    // d_in[10] (offset3) is a uniform pre-softmax shift -> cancels; unused.

    float* out = (float*)d_out;
    float* ws  = (float*)d_ws;
    float* GT   = ws + WS_GT;
    float* part = ws + WS_PART;

    g_kernel<<<9, 256, 0, stream>>>(Wq1, Wq2, Wq3, Wk1, Wk2, Wk3, GT, part);
    score_kernel<<<2048, 256, 0, stream>>>(x, GT, part);
    out_kernel<<<6144, 256, 0, stream>>>(x, part, logdet, off, off2, out, out + OUT0);
}